// Round 4
// baseline (315.790 us; speedup 1.0000x reference)
//
#include <hip/hip_runtime.h>

// VectorCollapseEngine R4: wave-per-row, barrier-free (R3 + compile fix:
// __builtin_nontemporal_store needs a native clang vector, not HIP float4).
// h_{l+1} = a*h_l + sum_k c_k dir_k  =>  h_final = A*h0 + sum_k W_k anchor_k.
// R2 was latency-bound (VALUBusy 29%, HBM 27%): tid==0 recurrence with IEEE
// sqrt/div chains stalled all 4 waves at __syncthreads. Now: each 64-lane wave
// owns one row — xor-butterfly reduction leaves sums in ALL lanes, recurrence
// runs redundantly per-wave (issue cost of 1 lane), v_rsq_f32 replaces
// sqrt+div chains. No __syncthreads, no LDS; waves fully independent.

typedef float nf4 __attribute__((ext_vector_type(4)));  // nontemporal-storable

constexpr int DIM = 4096;
constexpr int BATCH = 8192;
constexpr int NLAYERS = 6;
constexpr int TPB = 256;
constexpr int WAVES = TPB / 64;          // 4 rows per block
constexpr int CPT = DIM / (64 * 4);      // float4 chunks per lane = 16
constexpr int GVPT = DIM / (TPB * 4);    // gram kernel chunks = 4

constexpr size_t HOUT = (size_t)BATCH * DIM;
constexpr size_t TRACE = (size_t)NLAYERS * BATCH * 3;
constexpr size_t OFF_ALIGN = HOUT;
constexpr size_t OFF_DIV   = HOUT + TRACE;
constexpr size_t OFF_TENS  = HOUT + 2 * TRACE;

__device__ __forceinline__ float wave_allred(float v) {
#pragma unroll
  for (int m = 1; m < 64; m <<= 1) v += __shfl_xor(v, m, 64);
  return v;  // every lane holds the full sum
}

__device__ __forceinline__ float wave_red(float v) {
#pragma unroll
  for (int off = 32; off > 0; off >>= 1) v += __shfl_down(v, off, 64);
  return v;
}

// ---- setup: anchor norms + Gram of normalized dirs -> ws[0..8] ----
// ws layout: [n0, n1, n2, G01, G02, G12, G00, G11, G22]
__global__ __launch_bounds__(TPB) void gram_kernel(
    const float* __restrict__ an0, const float* __restrict__ an1,
    const float* __restrict__ an2, float* __restrict__ ws) {
  const int tid = threadIdx.x;
  float r[6];
#pragma unroll
  for (int i = 0; i < 6; ++i) r[i] = 0.f;
#pragma unroll
  for (int j = 0; j < GVPT; ++j) {
    const int idx = (tid + j * TPB) * 4;
    const float4 x = *(const float4*)(an0 + idx);
    const float4 y = *(const float4*)(an1 + idx);
    const float4 z = *(const float4*)(an2 + idx);
    r[0] += x.x*x.x + x.y*x.y + x.z*x.z + x.w*x.w;
    r[1] += y.x*y.x + y.y*y.y + y.z*y.z + y.w*y.w;
    r[2] += z.x*z.x + z.y*z.y + z.z*z.z + z.w*z.w;
    r[3] += x.x*y.x + x.y*y.y + x.z*y.z + x.w*y.w;
    r[4] += x.x*z.x + x.y*z.y + x.z*z.z + x.w*z.w;
    r[5] += y.x*z.x + y.y*z.y + y.z*z.z + y.w*z.w;
  }
  __shared__ float lds[4][6];
  const int lane = tid & 63, wv = tid >> 6;
#pragma unroll
  for (int i = 0; i < 6; ++i) r[i] = wave_red(r[i]);
  if (lane == 0) {
#pragma unroll
    for (int i = 0; i < 6; ++i) lds[wv][i] = r[i];
  }
  __syncthreads();
  if (tid == 0) {
#pragma unroll
    for (int i = 0; i < 6; ++i)
      r[i] = lds[0][i] + lds[1][i] + lds[2][i] + lds[3][i];
    const float n0 = fmaxf(sqrtf(r[0]), 1e-12f);
    const float n1 = fmaxf(sqrtf(r[1]), 1e-12f);
    const float n2 = fmaxf(sqrtf(r[2]), 1e-12f);
    ws[0] = n0; ws[1] = n1; ws[2] = n2;
    ws[3] = r[3] / (n0 * n1);
    ws[4] = r[4] / (n0 * n2);
    ws[5] = r[5] / (n1 * n2);
    ws[6] = r[0] / (n0 * n0);
    ws[7] = r[1] / (n1 * n1);
    ws[8] = r[2] / (n2 * n2);
  }
}

__global__ __launch_bounds__(TPB, 4) void collapse_kernel(
    const float* __restrict__ h0,
    const float* __restrict__ an0,
    const float* __restrict__ an1,
    const float* __restrict__ an2,
    const float* __restrict__ ws,
    float* __restrict__ out) {
  const int lane = threadIdx.x & 63;
  const int wv = threadIdx.x >> 6;
  const int b = blockIdx.x * WAVES + wv;
  const float* hrow = h0 + (size_t)b * DIM;

  // ---- pass 1: row dots {|h|^2, h.a0, h.a1, h.a2}; h stays in registers ----
  float4 hv[CPT];
  float r0 = 0.f, r1 = 0.f, r2 = 0.f, r3 = 0.f;
#pragma unroll
  for (int j = 0; j < CPT; ++j) {
    const int idx = (lane + j * 64) * 4;
    hv[j] = *(const float4*)(hrow + idx);
    const float4 x = *(const float4*)(an0 + idx);
    const float4 y = *(const float4*)(an1 + idx);
    const float4 z = *(const float4*)(an2 + idx);
    const float4 h = hv[j];
    r0 += h.x*h.x + h.y*h.y + h.z*h.z + h.w*h.w;
    r1 += h.x*x.x + h.y*x.y + h.z*x.z + h.w*x.w;
    r2 += h.x*y.x + h.y*y.y + h.z*y.z + h.w*y.w;
    r3 += h.x*z.x + h.y*z.y + h.z*z.z + h.w*z.w;
  }
  r0 = wave_allred(r0);
  r1 = wave_allred(r1);
  r2 = wave_allred(r2);
  r3 = wave_allred(r3);

  // ---- per-wave recurrence, all 64 lanes redundant (single issue) ----
  const float n0 = ws[0], n1 = ws[1], n2 = ws[2];
  float G[3][3];
  G[0][1] = G[1][0] = ws[3];
  G[0][2] = G[2][0] = ws[4];
  G[1][2] = G[2][1] = ws[5];
  G[0][0] = ws[6]; G[1][1] = ws[7]; G[2][2] = ws[8];

  const float str[3] = {0.1f, 0.1f, 0.05f};
  float s = r0;
  float d[3] = {r1 * __builtin_amdgcn_rcpf(n0),
                r2 * __builtin_amdgcn_rcpf(n1),
                r3 * __builtin_amdgcn_rcpf(n2)};
  float A = 1.f;
  float B[3] = {0.f, 0.f, 0.f};

#pragma unroll
  for (int l = 0; l < NLAYERS; ++l) {
    const float inv_hn = __builtin_amdgcn_rsqf(s);  // s > 0 in practice
    float al[3], dv[3], c[3];
#pragma unroll
    for (int k = 0; k < 3; ++k) {
      al[k] = d[k] * inv_hn;
      dv[k] = 1.f - al[k];
      const float rrsq = s - 2.f * d[k] + G[k][k];
      c[k] = str[k] * dv[k] * __builtin_amdgcn_rsqf(fmaxf(rrsq, 1e-24f));
    }
    if (lane == 0) {
#pragma unroll
      for (int k = 0; k < 3; ++k) {
        const size_t o = (size_t)l * (BATCH * 3) + (size_t)b * 3 + k;
        out[OFF_ALIGN + o] = al[k];
        out[OFF_DIV + o]   = dv[k];
        out[OFF_TENS + o]  = fmaxf(dv[k], 0.f);
      }
    }
    const float a = 1.f - (c[0] + c[1] + c[2]);
    float dn[3];
#pragma unroll
    for (int j = 0; j < 3; ++j)
      dn[j] = a * d[j] + c[0] * G[0][j] + c[1] * G[1][j] + c[2] * G[2][j];
    float sn = a * a * s + 2.f * a * (c[0]*d[0] + c[1]*d[1] + c[2]*d[2]);
#pragma unroll
    for (int k = 0; k < 3; ++k)
#pragma unroll
      for (int j = 0; j < 3; ++j) sn += c[k] * c[j] * G[k][j];
    A = a * A;
#pragma unroll
    for (int j = 0; j < 3; ++j) B[j] = a * B[j] + c[j];
    s = sn;
#pragma unroll
    for (int j = 0; j < 3; ++j) d[j] = dn[j];
    if (s > 100.0f) {  // ||h|| > 10
      const float hn2 = s * __builtin_amdgcn_rsqf(s);  // sqrt(s)
      const float sc = 10.0f * __builtin_amdgcn_rcpf(hn2 + 1e-8f);
      A *= sc;
#pragma unroll
      for (int j = 0; j < 3; ++j) { B[j] *= sc; d[j] *= sc; }
      s *= sc * sc;
    }
  }

  const float w0 = B[0] * __builtin_amdgcn_rcpf(n0);
  const float w1 = B[1] * __builtin_amdgcn_rcpf(n1);
  const float w2 = B[2] * __builtin_amdgcn_rcpf(n2);

  // ---- pass 2: h from registers; anchors re-read (L1/L2-hot) ----
  float* orow = out + (size_t)b * DIM;
#pragma unroll
  for (int j = 0; j < CPT; ++j) {
    const int idx = (lane + j * 64) * 4;
    const float4 x = *(const float4*)(an0 + idx);
    const float4 y = *(const float4*)(an1 + idx);
    const float4 z = *(const float4*)(an2 + idx);
    const float4 h = hv[j];
    nf4 o;
    o.x = A * h.x + w0 * x.x + w1 * y.x + w2 * z.x;
    o.y = A * h.y + w0 * x.y + w1 * y.y + w2 * z.y;
    o.z = A * h.z + w0 * x.z + w1 * y.z + w2 * z.z;
    o.w = A * h.w + w0 * x.w + w1 * y.w + w2 * z.w;
    __builtin_nontemporal_store(o, (nf4*)(orow + idx));
  }
}

extern "C" void kernel_launch(void* const* d_in, const int* in_sizes, int n_in,
                              void* d_out, int out_size, void* d_ws, size_t ws_size,
                              hipStream_t stream) {
  const float* h0  = (const float*)d_in[0];
  const float* an0 = (const float*)d_in[1];
  const float* an1 = (const float*)d_in[2];
  const float* an2 = (const float*)d_in[3];
  float* out = (float*)d_out;
  float* ws  = (float*)d_ws;
  gram_kernel<<<1, TPB, 0, stream>>>(an0, an1, an2, ws);
  collapse_kernel<<<BATCH / WAVES, TPB, 0, stream>>>(h0, an0, an1, an2, ws, out);
}